// Round 5
// baseline (41439.639 us; speedup 1.0000x reference)
//
#include <hip/hip_runtime.h>
#include <hip/hip_bf16.h>
#include <math.h>

#define T_STEPS 8192
#define M_DIM   1024
#define N_DIM   2048

typedef unsigned long long u64;
typedef unsigned int u32;

// ---------------- Kernel A: pre = X @ W_ih^T + (b_ih + b_hh) ----------------
__global__ __launch_bounds__(256) void pre_gemm(
    const float* __restrict__ X, const float* __restrict__ Wih,
    const float* __restrict__ bih, const float* __restrict__ bhh,
    float* __restrict__ out)
{
  __shared__ float As[128][36];
  __shared__ float Bs[128][36];
  const int tid = threadIdx.x;
  const int tx = tid & 15;
  const int ty = tid >> 4;
  const int bt = blockIdx.x * 128;
  const int bn = blockIdx.y * 128;

  float acc[8][8];
  #pragma unroll
  for (int i = 0; i < 8; ++i)
    #pragma unroll
    for (int j = 0; j < 8; ++j) acc[i][j] = 0.f;

  for (int k0 = 0; k0 < M_DIM; k0 += 32) {
    #pragma unroll
    for (int s = 0; s < 4; ++s) {
      int slot = tid + s * 256;
      int row  = slot >> 3;
      int c4   = (slot & 7) << 2;
      float4 va = *(const float4*)&X  [(size_t)(bt + row) * M_DIM + k0 + c4];
      float4 vb = *(const float4*)&Wih[(size_t)(bn + row) * M_DIM + k0 + c4];
      *(float4*)&As[row][c4] = va;
      *(float4*)&Bs[row][c4] = vb;
    }
    __syncthreads();
    #pragma unroll
    for (int kk = 0; kk < 32; kk += 4) {
      float4 a4[8], b4[8];
      #pragma unroll
      for (int i = 0; i < 8; ++i) a4[i] = *(const float4*)&As[ty + 16 * i][kk];
      #pragma unroll
      for (int j = 0; j < 8; ++j) b4[j] = *(const float4*)&Bs[tx + 16 * j][kk];
      #pragma unroll
      for (int i = 0; i < 8; ++i)
        #pragma unroll
        for (int j = 0; j < 8; ++j) {
          acc[i][j] = fmaf(a4[i].x, b4[j].x, acc[i][j]);
          acc[i][j] = fmaf(a4[i].y, b4[j].y, acc[i][j]);
          acc[i][j] = fmaf(a4[i].z, b4[j].z, acc[i][j]);
          acc[i][j] = fmaf(a4[i].w, b4[j].w, acc[i][j]);
        }
    }
    __syncthreads();
  }

  float bsum[8];
  #pragma unroll
  for (int j = 0; j < 8; ++j) {
    int col = bn + tx + 16 * j;
    bsum[j] = bih[col] + bhh[col];
  }
  #pragma unroll
  for (int i = 0; i < 8; ++i) {
    int rowg = bt + ty + 16 * i;
    #pragma unroll
    for (int j = 0; j < 8; ++j)
      out[(size_t)rowg * N_DIM + bn + tx + 16 * j] = acc[i][j] + bsum[j];
  }
}

// ---------------- Kernel B: persistent recurrence, flag+data handshake ------
// 256 blocks x 256 threads; block b owns rows [8b,8b+8) of W_hh in registers.
// Per step: producer stores 8 h-floats (one coalesced 32B sc-store), drains
// vmcnt(0), then stores ONE tagged flag. Consumers poll only their 4 producer
// flags (1 coalesced request/wave) and load each producer's data u64 the
// moment its flag lands. All atomics RELAXED agent-scope (no cache
// maintenance); ordering = drain-before-flag + in-order issue + compiler
// barrier. Skew <= 1 step by the flag dependency => double buffer race-free.
// Y[t-1] written as full 8KB coalesced plain-cached rows by block (t % 256)
// (single writer per line => no false sharing, no sc write amplification).
__global__ __launch_bounds__(256) void rnn_persist(
    const float* __restrict__ Whh,
    float* __restrict__ Y,        // d_out: pre[t] until overwritten with h_{t+1}
    float* __restrict__ hdata,    // 2 phases x 2048 floats, zeroed => h_0 = 0
    u32* __restrict__ flags)      // 2 phases x 256 tags, zeroed
{
  __shared__ float h_lds[N_DIM];
  __shared__ float hstage[8];
  const int tid  = threadIdx.x;
  const int b    = blockIdx.x;
  const int r    = tid >> 5;
  const int c    = tid & 31;
  const int grow = b * 8 + r;     // global output row
  const int f0   = tid >> 2;      // first producer-flag index (0..63), +64*i

  float w[64];
  #pragma unroll
  for (int k = 0; k < 64; ++k)
    w[k] = Whh[(size_t)grow * N_DIM + c + 32 * k];

  for (int t = 0; t < T_STEPS; ++t) {
    const int p = t & 1;

    // pre[t] for this row (plain cached; latency hides under the poll)
    float prev_pre = 0.f;
    if (c == 0) prev_pre = Y[(size_t)t * N_DIM + grow];

    // Wait for my 4 producer blocks; load each data u64 as its flag lands.
    // u64 j = tid + 256*i covers rows {2j, 2j+1}, produced by block j/4 =
    // tid/4 + 64*i — exactly flag f0 + 64*i.
    u64 hd[4];
    const u64* hsrc = (const u64*)(hdata + p * N_DIM);
    {
      const u32 need = (u32)t;
      unsigned pend = 0xFu;
      while (pend) {
        #pragma unroll
        for (int i = 0; i < 4; ++i)
          if (pend & (1u << i)) {
            u32 v = __hip_atomic_load(&flags[p * 256 + f0 + 64 * i],
                                      __ATOMIC_RELAXED, __HIP_MEMORY_SCOPE_AGENT);
            if (v >= need) {
              asm volatile("" ::: "memory");   // don't hoist data load above flag
              hd[i] = __hip_atomic_load(&hsrc[tid + 256 * i],
                                        __ATOMIC_RELAXED, __HIP_MEMORY_SCOPE_AGENT);
              pend &= ~(1u << i);
            }
          }
      }
    }
    #pragma unroll
    for (int i = 0; i < 4; ++i)
      ((u64*)h_lds)[tid + 256 * i] = hd[i];
    __syncthreads();                       // B: h_lds ready

    // y[grow] = sum_j W[grow][j] * h[j]  (conflict-free LDS reads)
    float acc = 0.f;
    #pragma unroll
    for (int k = 0; k < 64; ++k)
      acc = fmaf(w[k], h_lds[c + 32 * k], acc);
    #pragma unroll
    for (int off = 16; off >= 1; off >>= 1)
      acc += __shfl_xor(acc, off, 64);

    // Delayed coalesced Y[t-1] write (full rows, plain cached, single writer)
    if (b == (t & 255) && t > 0) {
      u64* yrow = (u64*)(Y + (size_t)(t - 1) * N_DIM);
      #pragma unroll
      for (int i = 0; i < 4; ++i)
        yrow[tid + 256 * i] = hd[i];
    }

    if (c == 0) {
      float hn = tanhf(acc + prev_pre);
      hstage[r] = hn;
    }
    __syncthreads();                       // C: hstage ready, h_lds/hd consumed

    // Publish: wave 0 lanes 0..7 — one 32B coalesced data store, drain, flag.
    if (tid < 8) {
      float v = hstage[tid];
      __hip_atomic_store(&hdata[((t + 1) & 1) * N_DIM + b * 8 + tid], v,
                         __ATOMIC_RELAXED, __HIP_MEMORY_SCOPE_AGENT);
      asm volatile("s_waitcnt vmcnt(0)" ::: "memory");
      if (tid == 0)
        __hip_atomic_store(&flags[((t + 1) & 1) * 256 + b], (u32)(t + 1),
                           __ATOMIC_RELAXED, __HIP_MEMORY_SCOPE_AGENT);
    }
  }

  // Epilogue: Y[T-1] = h_T (tag T, phase 0), written by block 0.
  if (b == 0) {
    const u32 need = (u32)T_STEPS;
    unsigned pend = 0xFu;
    u64 hd[4];
    const u64* hsrc = (const u64*)(hdata + 0 * N_DIM);
    while (pend) {
      #pragma unroll
      for (int i = 0; i < 4; ++i)
        if (pend & (1u << i)) {
          u32 v = __hip_atomic_load(&flags[0 * 256 + f0 + 64 * i],
                                    __ATOMIC_RELAXED, __HIP_MEMORY_SCOPE_AGENT);
          if (v >= need) {
            asm volatile("" ::: "memory");
            hd[i] = __hip_atomic_load(&hsrc[tid + 256 * i],
                                      __ATOMIC_RELAXED, __HIP_MEMORY_SCOPE_AGENT);
            pend &= ~(1u << i);
          }
        }
    }
    u64* yrow = (u64*)(Y + (size_t)(T_STEPS - 1) * N_DIM);
    #pragma unroll
    for (int i = 0; i < 4; ++i)
      yrow[tid + 256 * i] = hd[i];
  }
}

extern "C" void kernel_launch(void* const* d_in, const int* in_sizes, int n_in,
                              void* d_out, int out_size, void* d_ws, size_t ws_size,
                              hipStream_t stream) {
  const float* X   = (const float*)d_in[0];
  const float* Wih = (const float*)d_in[1];
  const float* Whh = (const float*)d_in[2];
  const float* bih = (const float*)d_in[3];
  const float* bhh = (const float*)d_in[4];
  float* Y = (float*)d_out;

  float* hdata = (float*)d_ws;                      // 2 x 2048 floats = 16 KB
  u32*   flags = (u32*)((char*)d_ws + 16384);       // 2 x 256 tags   =  2 KB

  // zero hdata (h_0 = 0) and flags (tag 0); ws is re-poisoned 0xAA each run
  hipMemsetAsync(d_ws, 0, 16384 + 2048, stream);

  dim3 gA(T_STEPS / 128, N_DIM / 128);              // (64, 16)
  pre_gemm<<<gA, dim3(256), 0, stream>>>(X, Wih, bih, bhh, Y);

  rnn_persist<<<dim3(256), dim3(256), 0, stream>>>(Whh, Y, hdata, flags);
}

// Round 8
// 28470.938 us; speedup vs baseline: 1.4555x; 1.4555x over previous
//
#include <hip/hip_runtime.h>
#include <hip/hip_bf16.h>
#include <math.h>

#define T_STEPS 8192
#define M_DIM   1024
#define N_DIM   2048

typedef unsigned long long u64;
typedef unsigned int u32;

// ---------------- Kernel A: pre = X @ W_ih^T + (b_ih + b_hh) ----------------
__global__ __launch_bounds__(256) void pre_gemm(
    const float* __restrict__ X, const float* __restrict__ Wih,
    const float* __restrict__ bih, const float* __restrict__ bhh,
    float* __restrict__ out)
{
  __shared__ float As[128][36];
  __shared__ float Bs[128][36];
  const int tid = threadIdx.x;
  const int tx = tid & 15;
  const int ty = tid >> 4;
  const int bt = blockIdx.x * 128;
  const int bn = blockIdx.y * 128;

  float acc[8][8];
  #pragma unroll
  for (int i = 0; i < 8; ++i)
    #pragma unroll
    for (int j = 0; j < 8; ++j) acc[i][j] = 0.f;

  for (int k0 = 0; k0 < M_DIM; k0 += 32) {
    #pragma unroll
    for (int s = 0; s < 4; ++s) {
      int slot = tid + s * 256;
      int row  = slot >> 3;
      int c4   = (slot & 7) << 2;
      float4 va = *(const float4*)&X  [(size_t)(bt + row) * M_DIM + k0 + c4];
      float4 vb = *(const float4*)&Wih[(size_t)(bn + row) * M_DIM + k0 + c4];
      *(float4*)&As[row][c4] = va;
      *(float4*)&Bs[row][c4] = vb;
    }
    __syncthreads();
    #pragma unroll
    for (int kk = 0; kk < 32; kk += 4) {
      float4 a4[8], b4[8];
      #pragma unroll
      for (int i = 0; i < 8; ++i) a4[i] = *(const float4*)&As[ty + 16 * i][kk];
      #pragma unroll
      for (int j = 0; j < 8; ++j) b4[j] = *(const float4*)&Bs[tx + 16 * j][kk];
      #pragma unroll
      for (int i = 0; i < 8; ++i)
        #pragma unroll
        for (int j = 0; j < 8; ++j) {
          acc[i][j] = fmaf(a4[i].x, b4[j].x, acc[i][j]);
          acc[i][j] = fmaf(a4[i].y, b4[j].y, acc[i][j]);
          acc[i][j] = fmaf(a4[i].z, b4[j].z, acc[i][j]);
          acc[i][j] = fmaf(a4[i].w, b4[j].w, acc[i][j]);
        }
    }
    __syncthreads();
  }

  float bsum[8];
  #pragma unroll
  for (int j = 0; j < 8; ++j) {
    int col = bn + tx + 16 * j;
    bsum[j] = bih[col] + bhh[col];
  }
  #pragma unroll
  for (int i = 0; i < 8; ++i) {
    int rowg = bt + ty + 16 * i;
    #pragma unroll
    for (int j = 0; j < 8; ++j)
      out[(size_t)rowg * N_DIM + bn + tx + 16 * j] = acc[i][j] + bsum[j];
  }
}

// ---------------- Kernel B: persistent recurrence ----------------
// 256 blocks x 256 threads; block b owns rows [8b,8b+8).
// One-hop tagged dataflow (R4 protocol): h element = u64 {tag, f32} in a
// double-buffered slot array; the sc-store IS the signal (all RELAXED agent
// scope, no cache maintenance, skew <= 1 step by construction).
// KEY change vs R4/R5: h NEVER goes through LDS. Thread tid's FMA columns are
// exactly its 8 polled slots {tid+256i}; W registers are laid out to match
// (wreg[row][i] = Whh[row][tid+256i]). FMA starts the moment this thread's
// polls land (overlaps stragglers). Reduction = one padded LDS scoreboard
// (8 conflict-free writes + 8 conflict-free strided reads + 5 shuffles),
// ~84 LDS-pipe ops/step/CU vs ~600 in R4 (which cost ~1.7us/step).
__global__ __launch_bounds__(256) void rnn_persist(
    const float* __restrict__ Whh,
    float* __restrict__ Y,        // d_out: pre[t] until overwritten with h_{t+1}
    u64* __restrict__ hbuf)       // 2 phases x 2048 tagged slots, zeroed
{
  __shared__ float part[256 * 9];   // [tid][r], stride 9 avoids bank aliasing
  const int tid = threadIdx.x;
  const int b   = blockIdx.x;
  const int r   = tid >> 5;         // row of this block handled in reduce: 0..7
  const int k   = tid & 31;         // reduction chunk within row

  // W fragment: wreg[row][i] = Whh[b*8+row][tid + 256*i]  (64 VGPRs)
  float wreg[8][8];
  #pragma unroll
  for (int rr = 0; rr < 8; ++rr)
    #pragma unroll
    for (int i = 0; i < 8; ++i)
      wreg[rr][i] = Whh[(size_t)(b * 8 + rr) * N_DIM + tid + 256 * i];

  for (int t = 0; t < T_STEPS; ++t) {
    const int p = t & 1;
    // pre[t] for the row this lane finalizes (k==0 lanes only)
    float ppre = 0.f;
    if (k == 0) ppre = Y[(size_t)t * N_DIM + b * 8 + r];

    const u64* __restrict__ src = hbuf + p * N_DIM;
    u64* __restrict__ dst = hbuf + (p ^ 1) * N_DIM;
    const u32 need = (u32)t;

    // poll own 8 slots (one-hop: packet carries tag AND data)
    float hv[8];
    unsigned pend = 0xffu;
    while (pend) {
      #pragma unroll
      for (int i = 0; i < 8; ++i)
        if (pend & (1u << i)) {
          u64 pk = __hip_atomic_load(&src[tid + 256 * i], __ATOMIC_RELAXED,
                                     __HIP_MEMORY_SCOPE_AGENT);
          if ((u32)(pk >> 32) >= need) {
            hv[i] = __uint_as_float((u32)pk);
            pend &= ~(1u << i);
          }
        }
    }

    // FMA straight from registers (no LDS staging); overlaps others' polls
    float acc[8];
    #pragma unroll
    for (int rr = 0; rr < 8; ++rr) {
      float a = 0.f;
      #pragma unroll
      for (int i = 0; i < 8; ++i) a = fmaf(wreg[rr][i], hv[i], a);
      acc[rr] = a;
    }
    #pragma unroll
    for (int rr = 0; rr < 8; ++rr) part[tid * 9 + rr] = acc[rr];

    // delayed coalesced Y[t-1] write, rotating owner (off critical path)
    if (t > 0 && b == (t & 255)) {
      #pragma unroll
      for (int i = 0; i < 8; ++i)
        Y[(size_t)(t - 1) * N_DIM + tid + 256 * i] = hv[i];
    }
    __syncthreads();

    // reduce row r over 256 threads: 8 strided reads (conflict-free) ...
    float s = 0.f;
    #pragma unroll
    for (int j = 0; j < 8; ++j)
      s += part[(k + 32 * j) * 9 + r];
    // ... then 5 xor-shuffles over the 32 k-lanes (stays in 32-group)
    #pragma unroll
    for (int off = 16; off >= 1; off >>= 1)
      s += __shfl_xor(s, off, 64);

    if (k == 0) {
      float hn = tanhf(s + ppre);
      u64 pk = ((u64)(u32)(t + 1) << 32) | (u64)__float_as_uint(hn);
      __hip_atomic_store(&dst[b * 8 + r], pk, __ATOMIC_RELAXED,
                         __HIP_MEMORY_SCOPE_AGENT);
    }
    __syncthreads();   // part[] consumed; safe to overwrite next step
  }

  // Epilogue: Y[T-1] = h_T (phase 0, tag T), written by block 0.
  if (b == 0) {
    const u32 need = (u32)T_STEPS;
    const u64* __restrict__ src = hbuf;     // phase 0
    float hv[8];
    unsigned pend = 0xffu;
    while (pend) {
      #pragma unroll
      for (int i = 0; i < 8; ++i)
        if (pend & (1u << i)) {
          u64 pk = __hip_atomic_load(&src[tid + 256 * i], __ATOMIC_RELAXED,
                                     __HIP_MEMORY_SCOPE_AGENT);
          if ((u32)(pk >> 32) >= need) {
            hv[i] = __uint_as_float((u32)pk);
            pend &= ~(1u << i);
          }
        }
    }
    #pragma unroll
    for (int i = 0; i < 8; ++i)
      Y[(size_t)(T_STEPS - 1) * N_DIM + tid + 256 * i] = hv[i];
  }
}

extern "C" void kernel_launch(void* const* d_in, const int* in_sizes, int n_in,
                              void* d_out, int out_size, void* d_ws, size_t ws_size,
                              hipStream_t stream) {
  const float* X   = (const float*)d_in[0];
  const float* Wih = (const float*)d_in[1];
  const float* Whh = (const float*)d_in[2];
  const float* bih = (const float*)d_in[3];
  const float* bhh = (const float*)d_in[4];
  float* Y = (float*)d_out;

  u64* hbuf = (u64*)d_ws;   // 2 x 2048 tagged slots = 32 KB

  // zero tagged slots: tag 0 + value 0.0 == h_0 (ws re-poisoned each run)
  hipMemsetAsync(d_ws, 0, 2 * N_DIM * sizeof(u64), stream);

  dim3 gA(T_STEPS / 128, N_DIM / 128);              // (64, 16)
  pre_gemm<<<gA, dim3(256), 0, stream>>>(X, Wih, bih, bhh, Y);

  rnn_persist<<<dim3(256), dim3(256), 0, stream>>>(Whh, Y, hbuf);
}